// Round 4
// baseline (16488.335 us; speedup 1.0000x reference)
//
#include <hip/hip_runtime.h>
#include <hip/hip_bf16.h>
#include <stdint.h>

#define B_ 64
#define S_ 512
#define E_ 300
#define H_ 512
#define NG_ 1536  // 3*H

// ---------------- init: zero h-state, r/y buffers, barrier counters ----------
__global__ __launch_bounds__(256) void k_init(unsigned* __restrict__ p) {
  int i = blockIdx.x * 256 + threadIdx.x;
  if (i < 98560) p[i] = 0u;  // hbuf(32768) + rbuf(32768) + ybuf(32768) + cnt(256) words
}

// ---------------- kernel A: Xzrh[s][b][g*512+c] = x_{b,s} @ Wg[H:,:] + b_g ---
__global__ __launch_bounds__(256) void k_xproj(
    const int* __restrict__ text, const float* __restrict__ emb,
    const float* __restrict__ Wz, const float* __restrict__ Wr,
    const float* __restrict__ Wh, const float* __restrict__ bz,
    const float* __restrict__ br, const float* __restrict__ bh,
    float* __restrict__ X)
{
  __shared__ float xs[32][304];   // 32 (b,s)-rows x 300 embed dims (padded)
  __shared__ int   toks[32];
  const int b  = blockIdx.x >> 4;         // batch row
  const int s0 = (blockIdx.x & 15) << 5;  // 32-step tile
  const int t  = threadIdx.x;

  if (t < 32) toks[t] = text[b * S_ + s0 + t];
  __syncthreads();
  for (int r = 0; r < 32; ++r) {
    const float* er = emb + (size_t)toks[r] * E_;
    for (int e = t; e < E_; e += 256) xs[r][e] = er[e];
  }
  __syncthreads();

  const int c = t & 63;   // output col within 64-chunk
  const int q = t >> 6;   // row quad: rows 8q..8q+7
  for (int n0 = 0; n0 < NG_; n0 += 64) {
    const int n  = n0 + c;
    const int g  = n >> 9;        // 0:z 1:r 2:h
    const int bc = n & 511;
    const float* Wg = (g == 0) ? Wz : (g == 1) ? Wr : Wh;
    const float* bg = (g == 0) ? bz : (g == 1) ? br : bh;
    float acc[8];
    const float bias = bg[bc];
    #pragma unroll
    for (int i = 0; i < 8; ++i) acc[i] = bias;
    for (int e = 0; e < E_; e += 4) {
      const float w0 = Wg[(size_t)(H_ + e) * H_ + bc];
      const float w1 = Wg[(size_t)(H_ + e + 1) * H_ + bc];
      const float w2 = Wg[(size_t)(H_ + e + 2) * H_ + bc];
      const float w3 = Wg[(size_t)(H_ + e + 3) * H_ + bc];
      #pragma unroll
      for (int i = 0; i < 8; ++i) {
        const float4 xv = *(const float4*)&xs[(q << 3) + i][e];
        acc[i] = fmaf(xv.w, w3, fmaf(xv.z, w2, fmaf(xv.y, w1, fmaf(xv.x, w0, acc[i]))));
      }
    }
    #pragma unroll
    for (int i = 0; i < 8; ++i) {
      const int s = s0 + (q << 3) + i;
      X[((size_t)s * B_ + b) * NG_ + n] = acc[i];
    }
  }
}

// ---------------- coherent (agent-scope, cache-bypassing) element access ----
__device__ __forceinline__ float ldg_coh(const float* p) {
  return __hip_atomic_load(p, __ATOMIC_RELAXED, __HIP_MEMORY_SCOPE_AGENT);
}
__device__ __forceinline__ void stg_coh(float* p, float v) {
  __hip_atomic_store(p, v, __ATOMIC_RELAXED, __HIP_MEMORY_SCOPE_AGENT);
}

// ---------------- fence-free intra-group barrier ---------------------------
// Correctness: all cross-block payloads are sc-coherent (agent-scope atomics),
// and __syncthreads drains each wave's vmcnt (stores globally visible) before
// thread 0 signals arrival. So no L2 writeback/invalidate is needed at all.
__device__ __forceinline__ void group_barrier(unsigned* c, unsigned expected) {
  __syncthreads();   // emits s_waitcnt vmcnt(0) lgkmcnt(0) + s_barrier
  if (threadIdx.x == 0) {
    __hip_atomic_fetch_add(c, 1u, __ATOMIC_RELAXED, __HIP_MEMORY_SCOPE_AGENT);
    while (__hip_atomic_load(c, __ATOMIC_RELAXED, __HIP_MEMORY_SCOPE_AGENT) < expected)
      __builtin_amdgcn_s_sleep(2);
  }
  __syncthreads();
}

// ---------------- kernel B: persistent recurrence --------------------------
// grid 256: group g = bid%8 (8 batch rows), col-block j = bid/8 owns H-cols [16j,16j+16)
// LDS: 99072(WT) + 16512(hs) + 512(zs) + 4096(pbuf) = 120192 B -> 1 block/CU
__global__ __launch_bounds__(256, 1) void k_gru(
    const float* __restrict__ Wz, const float* __restrict__ Wr,
    const float* __restrict__ Wh, const float* __restrict__ X,
    float* __restrict__ hb, float* __restrict__ rb,
    float* __restrict__ yb, unsigned* __restrict__ cnt)
{
  __shared__ float  WT[48][516];  // [gate*16+c][k] transposed weights (99 KB)
  __shared__ float  hs[8][516];   // h for the group's 8 rows; becomes r*h in phase 2
  __shared__ float  zs[8][16];    // own z slice
  __shared__ float4 pbuf[256];    // K-split partials (shared by phase 1 / phase 2)

  const int t = threadIdx.x;
  const int g = blockIdx.x & 7;
  const int j = blockIdx.x >> 3;
  const int colblk = j << 4;
  const int b0 = g << 3;

  float* hbuf = hb + g * (8 * H_);
  float* rbuf = rb + g * (8 * H_);
  unsigned* bar = cnt + g * 32;   // 128B-separated counters

  // one-time: weights -> LDS (transposed so K is contiguous per gate-col)
  for (int idx = t; idx < 48 * 512; idx += 256) {
    const int gc = idx >> 9;
    const int k  = idx & 511;
    const float* Wsel = (gc < 16) ? Wz : (gc < 32) ? Wr : Wh;
    WT[gc][k] = Wsel[(size_t)k * H_ + colblk + (gc & 15)];
  }

  // ---- phase-1 compute mapping: 2 rows x 2 gate-cols per thread, K/4 split
  const int og  = t & 63;         // output group
  const int ksi = t >> 6;         // 0..3 -> K slice [128*ksi, +128)
  const int rp  = og & 3;         // row pair: rows 2rp, 2rp+1
  const int cp  = og >> 2;        // col pair: gcols 2cp, 2cp+1 (0..31; z:0..15 r:16..31)
  // ---- phase-1 finisher mapping: one output per thread
  const int ogf   = t >> 2;
  const int ef    = t & 3;
  const int rowf  = ((ogf & 3) << 1) + (ef >> 1);
  const int gcolf = ((ogf >> 2) << 1) + (ef & 1);     // 0..31
  const int gatef = gcolf >> 4;                       // 0:z 1:r
  const int cf    = gcolf & 15;
  // ---- phase-2 compute mapping: 2 rows x 2 cols per thread, K/8 split
  const int og2  = t & 31;
  const int ksi2 = t >> 5;        // 0..7 -> K slice [64*ksi2, +64)
  const int rp2  = og2 & 3;
  const int cp2  = og2 >> 2;      // 0..7 -> cols 2cp2, 2cp2+1
  // ---- phase-2 finisher mapping (t < 128): one output per thread
  const int rowf2 = (((t >> 2) & 3) << 1) + ((t & 3) >> 1);
  const int cf2   = (((t >> 2) >> 2) << 1) + (t & 1);

  const float* pf = (const float*)pbuf;
  unsigned nbar = 0;
  __syncthreads();

  for (int s = 0; s < S_; ++s) {
    // stage h (global -> LDS) via coherent loads; idx = t + 256u is coalesced
    #pragma unroll
    for (int u = 0; u < 16; ++u) {
      const int idx = t + (u << 8);
      hs[idx >> 9][idx & 511] = ldg_coh(&hbuf[idx]);
    }
    __syncthreads();

    const float* Xs = X + ((size_t)s * B_ + b0) * NG_;
    const float xv1 = Xs[rowf * NG_ + gatef * H_ + colblk + cf];
    const float xv2 = (t < 128) ? Xs[rowf2 * NG_ + 2 * H_ + colblk + cf2] : 0.f;

    // ---- phase 1: z,r = sigmoid(h @ W + X) ; 2x2 block, K-split 4 ----
    {
      float p00 = 0.f, p01 = 0.f, p10 = 0.f, p11 = 0.f;
      const float* h0 = &hs[(rp << 1) + 0][0];
      const float* h1 = &hs[(rp << 1) + 1][0];
      const float* w0 = &WT[(cp << 1) + 0][0];
      const float* w1 = &WT[(cp << 1) + 1][0];
      const int k0 = ksi << 7;
      #pragma unroll 4
      for (int k = k0; k < k0 + 128; k += 4) {
        const float4 a = *(const float4*)&h0[k];
        const float4 b = *(const float4*)&h1[k];
        const float4 u = *(const float4*)&w0[k];
        const float4 v = *(const float4*)&w1[k];
        p00 = fmaf(a.x,u.x,p00); p00 = fmaf(a.y,u.y,p00); p00 = fmaf(a.z,u.z,p00); p00 = fmaf(a.w,u.w,p00);
        p01 = fmaf(a.x,v.x,p01); p01 = fmaf(a.y,v.y,p01); p01 = fmaf(a.z,v.z,p01); p01 = fmaf(a.w,v.w,p01);
        p10 = fmaf(b.x,u.x,p10); p10 = fmaf(b.y,u.y,p10); p10 = fmaf(b.z,u.z,p10); p10 = fmaf(b.w,u.w,p10);
        p11 = fmaf(b.x,v.x,p11); p11 = fmaf(b.y,v.y,p11); p11 = fmaf(b.z,v.z,p11); p11 = fmaf(b.w,v.w,p11);
      }
      pbuf[(ksi << 6) + og] = make_float4(p00, p01, p10, p11);
    }
    __syncthreads();
    {
      // finisher: sum 4 K-partials, add X, sigmoid, publish coherently
      const float sum = pf[t] + pf[256 + t] + pf[512 + t] + pf[768 + t];
      const float pre = sum + xv1;
      const float sig = 1.f / (1.f + __expf(-pre));
      if (gatef == 0) zs[rowf][cf] = sig;                    // z stays block-local
      else stg_coh(&rbuf[rowf * H_ + colblk + cf], sig);     // publish r group-wide
    }

    group_barrier(bar, 32u * (++nbar));                      // r visible group-wide

    // snapshot pre-overwrite h and z for the finisher threads
    float hold = 0.f, zv = 0.f;
    if (t < 128) { hold = hs[rowf2][colblk + cf2]; zv = zs[rowf2][cf2]; }
    __syncthreads();

    // hs <- r * h  (in place), r read coherently; same arithmetic order
    #pragma unroll
    for (int u = 0; u < 16; ++u) {
      const int idx = t + (u << 8);
      const int rr = idx >> 9, kk = idx & 511;
      hs[rr][kk] *= ldg_coh(&rbuf[idx]);
    }
    __syncthreads();

    // ---- phase 2: y = tanh((r*h) @ Wh + Xh) ; 2x2 block, K-split 8 ----
    {
      float p00 = 0.f, p01 = 0.f, p10 = 0.f, p11 = 0.f;
      const float* h0 = &hs[(rp2 << 1) + 0][0];
      const float* h1 = &hs[(rp2 << 1) + 1][0];
      const float* w0 = &WT[32 + (cp2 << 1) + 0][0];
      const float* w1 = &WT[32 + (cp2 << 1) + 1][0];
      const int k0 = ksi2 << 6;
      #pragma unroll 4
      for (int k = k0; k < k0 + 64; k += 4) {
        const float4 a = *(const float4*)&h0[k];
        const float4 b = *(const float4*)&h1[k];
        const float4 u = *(const float4*)&w0[k];
        const float4 v = *(const float4*)&w1[k];
        p00 = fmaf(a.x,u.x,p00); p00 = fmaf(a.y,u.y,p00); p00 = fmaf(a.z,u.z,p00); p00 = fmaf(a.w,u.w,p00);
        p01 = fmaf(a.x,v.x,p01); p01 = fmaf(a.y,v.y,p01); p01 = fmaf(a.z,v.z,p01); p01 = fmaf(a.w,v.w,p01);
        p10 = fmaf(b.x,u.x,p10); p10 = fmaf(b.y,u.y,p10); p10 = fmaf(b.z,u.z,p10); p10 = fmaf(b.w,u.w,p10);
        p11 = fmaf(b.x,v.x,p11); p11 = fmaf(b.y,v.y,p11); p11 = fmaf(b.z,v.z,p11); p11 = fmaf(b.w,v.w,p11);
      }
      pbuf[(ksi2 << 5) + og2] = make_float4(p00, p01, p10, p11);
    }
    __syncthreads();
    if (t < 128) {
      // finisher: sum 8 K-partials, tanh, h update (published coherently)
      float sum = pf[t];
      #pragma unroll
      for (int q = 1; q < 8; ++q) sum += pf[(q << 7) + t];
      const float pre = sum + xv2;
      const float ex  = __expf(2.f * pre);
      const float y   = (ex - 1.f) / (ex + 1.f);
      const float hnew = (1.f - zv) * hold + zv * y;
      stg_coh(&hbuf[rowf2 * H_ + colblk + cf2], hnew);
      if (s == S_ - 1) yb[(b0 + rowf2) * H_ + colblk + cf2] = y;  // read by k_dense
    }

    group_barrier(bar, 32u * (++nbar));                      // h_new visible group-wide
  }
}

// ---------------- dense head: out = y_T @ dense_W + dense_b ----------------
__global__ __launch_bounds__(256) void k_dense(
    const float* __restrict__ yb, const float* __restrict__ dW,
    const float* __restrict__ db, float* __restrict__ out)
{
  const int t = threadIdx.x;
  if (t >= 192) return;
  const int b = t / 3, p = t % 3;
  float acc = db[p];
  const float* yr = yb + b * H_;
  for (int k = 0; k < H_; ++k) acc = fmaf(yr[k], dW[k * 3 + p], acc);
  out[b * 3 + p] = acc;
}

// ---------------- launcher -------------------------------------------------
extern "C" void kernel_launch(void* const* d_in, const int* in_sizes, int n_in,
                              void* d_out, int out_size, void* d_ws, size_t ws_size,
                              hipStream_t stream) {
  const int*   text = (const int*)d_in[0];
  const float* emb  = (const float*)d_in[1];
  const float* Wz   = (const float*)d_in[2];
  const float* bz   = (const float*)d_in[3];
  const float* Wr   = (const float*)d_in[4];
  const float* br   = (const float*)d_in[5];
  const float* Wh   = (const float*)d_in[6];
  const float* bh   = (const float*)d_in[7];
  const float* dW   = (const float*)d_in[8];
  const float* db   = (const float*)d_in[9];
  float* out = (float*)d_out;

  // workspace layout
  float*    X    = (float*)d_ws;                                   // 201,326,592 B
  float*    hbp  = (float*)((char*)d_ws + (size_t)201326592);      // 8*8*512 f32
  float*    rbp  = hbp + 32768;
  float*    ybp  = rbp + 32768;
  unsigned* cntp = (unsigned*)(ybp + 32768);                       // 1024 B

  hipLaunchKernelGGL(k_init, dim3(385), dim3(256), 0, stream, (unsigned*)hbp);

  hipLaunchKernelGGL(k_xproj, dim3(1024), dim3(256), 0, stream,
                     text, emb, Wz, Wr, Wh, bz, br, bh, X);

  const float* Wz_ = Wz; const float* Wr_ = Wr; const float* Wh_ = Wh;
  const float* X_ = X; float* hb_ = hbp; float* rb_ = rbp; float* yb_ = ybp;
  unsigned* cnt_ = cntp;
  void* kargs[] = { (void*)&Wz_, (void*)&Wr_, (void*)&Wh_, (void*)&X_,
                    (void*)&hb_, (void*)&rb_, (void*)&yb_, (void*)&cnt_ };
  hipLaunchCooperativeKernel((void*)k_gru, dim3(256), dim3(256), kargs, 0, stream);

  hipLaunchKernelGGL(k_dense, dim3(1), dim3(256), 0, stream, ybp, dW, db, out);
}

// Round 7
// 7011.216 us; speedup vs baseline: 2.3517x; 2.3517x over previous
//
#include <hip/hip_runtime.h>
#include <hip/hip_bf16.h>
#include <stdint.h>

#define B_ 64
#define S_ 512
#define E_ 300
#define H_ 512
#define NG_ 1536  // 3*H

// ---------------- init: zero h-state, r/y buffers, flags ---------------------
// hbuf(32768) + rbuf(32768) + ybuf(32768) + flags(8 groups * 32 slots * 8 = 2048) words
__global__ __launch_bounds__(256) void k_init(unsigned* __restrict__ p) {
  int i = blockIdx.x * 256 + threadIdx.x;
  if (i < 100352) p[i] = 0u;
}

// ---------------- kernel A: Xzrh[s][b][g*512+c] = x_{b,s} @ Wg[H:,:] + b_g ---
__global__ __launch_bounds__(256) void k_xproj(
    const int* __restrict__ text, const float* __restrict__ emb,
    const float* __restrict__ Wz, const float* __restrict__ Wr,
    const float* __restrict__ Wh, const float* __restrict__ bz,
    const float* __restrict__ br, const float* __restrict__ bh,
    float* __restrict__ X)
{
  __shared__ float xs[32][304];   // 32 (b,s)-rows x 300 embed dims (padded)
  __shared__ int   toks[32];
  const int b  = blockIdx.x >> 4;         // batch row
  const int s0 = (blockIdx.x & 15) << 5;  // 32-step tile
  const int t  = threadIdx.x;

  if (t < 32) toks[t] = text[b * S_ + s0 + t];
  __syncthreads();
  for (int r = 0; r < 32; ++r) {
    const float* er = emb + (size_t)toks[r] * E_;
    for (int e = t; e < E_; e += 256) xs[r][e] = er[e];
  }
  __syncthreads();

  const int c = t & 63;   // output col within 64-chunk
  const int q = t >> 6;   // row quad: rows 8q..8q+7
  for (int n0 = 0; n0 < NG_; n0 += 64) {
    const int n  = n0 + c;
    const int g  = n >> 9;        // 0:z 1:r 2:h
    const int bc = n & 511;
    const float* Wg = (g == 0) ? Wz : (g == 1) ? Wr : Wh;
    const float* bg = (g == 0) ? bz : (g == 1) ? br : bh;
    float acc[8];
    const float bias = bg[bc];
    #pragma unroll
    for (int i = 0; i < 8; ++i) acc[i] = bias;
    for (int e = 0; e < E_; e += 4) {
      const float w0 = Wg[(size_t)(H_ + e) * H_ + bc];
      const float w1 = Wg[(size_t)(H_ + e + 1) * H_ + bc];
      const float w2 = Wg[(size_t)(H_ + e + 2) * H_ + bc];
      const float w3 = Wg[(size_t)(H_ + e + 3) * H_ + bc];
      #pragma unroll
      for (int i = 0; i < 8; ++i) {
        const float4 xv = *(const float4*)&xs[(q << 3) + i][e];
        acc[i] = fmaf(xv.w, w3, fmaf(xv.z, w2, fmaf(xv.y, w1, fmaf(xv.x, w0, acc[i]))));
      }
    }
    #pragma unroll
    for (int i = 0; i < 8; ++i) {
      const int s = s0 + (q << 3) + i;
      X[((size_t)s * B_ + b) * NG_ + n] = acc[i];
    }
  }
}

// ---------------- coherent access primitives (intrinsics only) --------------
__device__ __forceinline__ unsigned ld_coh_u32(const unsigned* p) {
  return __hip_atomic_load(p, __ATOMIC_RELAXED, __HIP_MEMORY_SCOPE_AGENT);
}
__device__ __forceinline__ void st_coh_u32(unsigned* p, unsigned v) {
  __hip_atomic_store(p, v, __ATOMIC_RELAXED, __HIP_MEMORY_SCOPE_AGENT);
}
__device__ __forceinline__ void st_coh_f32(float* p, float v) {
  __hip_atomic_store(p, v, __ATOMIC_RELAXED, __HIP_MEMORY_SCOPE_AGENT);
}
// stage 8*512 floats group-state via u64 coherent loads: 8 loads/thread,
// each covering one 516-padded LDS row. e = 2t + 512u -> row u, col 2t.
__device__ __forceinline__ void stage_coh(const float* src, float (*dst)[516], int t) {
  #pragma unroll
  for (int u = 0; u < 8; ++u) {
    const int e = (t << 1) + (u << 9);
    const unsigned long long v = __hip_atomic_load(
        (const unsigned long long*)(src + e), __ATOMIC_RELAXED, __HIP_MEMORY_SCOPE_AGENT);
    *(unsigned long long*)&dst[u][t << 1] = v;
  }
}

// ---------------- contention-free flag barrier (no RMW, no fences) ----------
// Arrival: relaxed agent store to OWN 32B-padded slot. Physical release: the
// preceding __syncthreads() emits s_waitcnt vmcnt(0) before s_barrier, so all
// coherent payload stores are ack'd at the coherence point before any thread
// arrives. Gather: lanes 0..31 of wave 0 poll all 32 flags in parallel
// (1 RTT per iteration, zero serialization). Iteration cap converts any
// visibility bug into a visible wrong-answer instead of a container hang.
__device__ __forceinline__ void group_barrier(unsigned* gflags, unsigned* myflag,
                                              unsigned gen) {
  __syncthreads();
  const int t = threadIdx.x;
  if (t < 64) {
    if (t == 0) st_coh_u32(myflag, gen);
    unsigned v;
    int it = 0;
    do {
      v = (t < 32) ? ld_coh_u32(gflags + t * 8) : gen;
    } while (__ballot(v < gen) && ++it < 4096);
  }
  __syncthreads();
}

// ---------------- kernel B: persistent recurrence --------------------------
// grid 256: group g = bid%8 (8 batch rows), col-block j = bid/8 owns H-cols [16j,16j+16)
// LDS: 99072(WT) + 16512(hs) + 512(zs) + 4096(pbuf) = 120192 B -> 1 block/CU
__global__ __launch_bounds__(256, 1) void k_gru(
    const float* __restrict__ Wz, const float* __restrict__ Wr,
    const float* __restrict__ Wh, const float* __restrict__ X,
    float* __restrict__ hb, float* __restrict__ rb,
    float* __restrict__ yb, unsigned* __restrict__ flags)
{
  __shared__ float  WT[48][516];  // [gate*16+c][k] transposed weights (99 KB)
  __shared__ float  hs[8][516];   // h for the group's 8 rows; becomes r*h in phase 2
  __shared__ float  zs[8][16];    // own z slice
  __shared__ float4 pbuf[256];    // K-split partials (shared by phase 1 / phase 2)

  const int t = threadIdx.x;
  const int g = blockIdx.x & 7;
  const int j = blockIdx.x >> 3;
  const int colblk = j << 4;
  const int b0 = g << 3;

  float* hbuf = hb + g * (8 * H_);
  float* rbuf = rb + g * (8 * H_);
  unsigned* gflags = flags + g * 256;    // 32 flags * 8-dword (32B) stride
  unsigned* myflag = gflags + j * 8;

  // one-time: weights -> LDS (transposed so K is contiguous per gate-col)
  for (int idx = t; idx < 48 * 512; idx += 256) {
    const int gc = idx >> 9;
    const int k  = idx & 511;
    const float* Wsel = (gc < 16) ? Wz : (gc < 32) ? Wr : Wh;
    WT[gc][k] = Wsel[(size_t)k * H_ + colblk + (gc & 15)];
  }

  // ---- phase-1 compute mapping: 2 rows x 2 gate-cols per thread, K/4 split
  const int og  = t & 63;         // output group
  const int ksi = t >> 6;         // 0..3 -> K slice [128*ksi, +128)
  const int rp  = og & 3;         // row pair: rows 2rp, 2rp+1
  const int cp  = og >> 2;        // col pair: gcols 2cp, 2cp+1 (0..31; z:0..15 r:16..31)
  // ---- phase-1 finisher mapping: one output per thread
  const int ogf   = t >> 2;
  const int ef    = t & 3;
  const int rowf  = ((ogf & 3) << 1) + (ef >> 1);
  const int gcolf = ((ogf >> 2) << 1) + (ef & 1);     // 0..31
  const int gatef = gcolf >> 4;                       // 0:z 1:r
  const int cf    = gcolf & 15;
  // ---- phase-2 compute mapping: 2 rows x 2 cols per thread, K/8 split
  const int og2  = t & 31;
  const int ksi2 = t >> 5;        // 0..7 -> K slice [64*ksi2, +64)
  const int rp2  = og2 & 3;
  const int cp2  = og2 >> 2;      // 0..7 -> cols 2cp2, 2cp2+1
  // ---- phase-2 finisher mapping (t < 128): one output per thread
  const int rowf2 = (((t >> 2) & 3) << 1) + ((t & 3) >> 1);
  const int cf2   = (((t >> 2) >> 2) << 1) + (t & 1);

  const float* pf = (const float*)pbuf;
  unsigned nbar = 0;
  __syncthreads();

  for (int s = 0; s < S_; ++s) {
    // stage h (coherent u64 loads) -> hs
    stage_coh(hbuf, hs, t);
    __syncthreads();

    const float* Xs = X + ((size_t)s * B_ + b0) * NG_;
    const float xv1 = Xs[rowf * NG_ + gatef * H_ + colblk + cf];
    const float xv2 = (t < 128) ? Xs[rowf2 * NG_ + 2 * H_ + colblk + cf2] : 0.f;

    // ---- phase 1: z,r = sigmoid(h @ W + X) ; 2x2 block, K-split 4 ----
    {
      float p00 = 0.f, p01 = 0.f, p10 = 0.f, p11 = 0.f;
      const float* h0 = &hs[(rp << 1) + 0][0];
      const float* h1 = &hs[(rp << 1) + 1][0];
      const float* w0 = &WT[(cp << 1) + 0][0];
      const float* w1 = &WT[(cp << 1) + 1][0];
      const int k0 = ksi << 7;
      #pragma unroll 4
      for (int k = k0; k < k0 + 128; k += 4) {
        const float4 a = *(const float4*)&h0[k];
        const float4 b = *(const float4*)&h1[k];
        const float4 u = *(const float4*)&w0[k];
        const float4 v = *(const float4*)&w1[k];
        p00 = fmaf(a.x,u.x,p00); p00 = fmaf(a.y,u.y,p00); p00 = fmaf(a.z,u.z,p00); p00 = fmaf(a.w,u.w,p00);
        p01 = fmaf(a.x,v.x,p01); p01 = fmaf(a.y,v.y,p01); p01 = fmaf(a.z,v.z,p01); p01 = fmaf(a.w,v.w,p01);
        p10 = fmaf(b.x,u.x,p10); p10 = fmaf(b.y,u.y,p10); p10 = fmaf(b.z,u.z,p10); p10 = fmaf(b.w,u.w,p10);
        p11 = fmaf(b.x,v.x,p11); p11 = fmaf(b.y,v.y,p11); p11 = fmaf(b.z,v.z,p11); p11 = fmaf(b.w,v.w,p11);
      }
      pbuf[(ksi << 6) + og] = make_float4(p00, p01, p10, p11);
    }
    __syncthreads();
    {
      // finisher: sum 4 K-partials, add X, sigmoid; publish r*h (not r) so
      // receivers skip the multiply pass
      const float sum = pf[t] + pf[256 + t] + pf[512 + t] + pf[768 + t];
      const float pre = sum + xv1;
      const float sig = 1.f / (1.f + __expf(-pre));
      if (gatef == 0) zs[rowf][cf] = sig;                              // z local
      else st_coh_f32(&rbuf[rowf * H_ + colblk + cf],
                      sig * hs[rowf][colblk + cf]);                    // publish r*h
    }

    group_barrier(gflags, myflag, ++nbar);                 // r*h visible group-wide

    // snapshot pre-overwrite h and z for the finisher threads
    float hold = 0.f, zv = 0.f;
    if (t < 128) { hold = hs[rowf2][colblk + cf2]; zv = zs[rowf2][cf2]; }
    __syncthreads();

    // stage r*h (coherent) -> hs, overwriting h
    stage_coh(rbuf, hs, t);
    __syncthreads();

    // ---- phase 2: y = tanh((r*h) @ Wh + Xh) ; 2x2 block, K-split 8 ----
    {
      float p00 = 0.f, p01 = 0.f, p10 = 0.f, p11 = 0.f;
      const float* h0 = &hs[(rp2 << 1) + 0][0];
      const float* h1 = &hs[(rp2 << 1) + 1][0];
      const float* w0 = &WT[32 + (cp2 << 1) + 0][0];
      const float* w1 = &WT[32 + (cp2 << 1) + 1][0];
      const int k0 = ksi2 << 6;
      #pragma unroll 4
      for (int k = k0; k < k0 + 64; k += 4) {
        const float4 a = *(const float4*)&h0[k];
        const float4 b = *(const float4*)&h1[k];
        const float4 u = *(const float4*)&w0[k];
        const float4 v = *(const float4*)&w1[k];
        p00 = fmaf(a.x,u.x,p00); p00 = fmaf(a.y,u.y,p00); p00 = fmaf(a.z,u.z,p00); p00 = fmaf(a.w,u.w,p00);
        p01 = fmaf(a.x,v.x,p01); p01 = fmaf(a.y,v.y,p01); p01 = fmaf(a.z,v.z,p01); p01 = fmaf(a.w,v.w,p01);
        p10 = fmaf(b.x,u.x,p10); p10 = fmaf(b.y,u.y,p10); p10 = fmaf(b.z,u.z,p10); p10 = fmaf(b.w,u.w,p10);
        p11 = fmaf(b.x,v.x,p11); p11 = fmaf(b.y,v.y,p11); p11 = fmaf(b.z,v.z,p11); p11 = fmaf(b.w,v.w,p11);
      }
      pbuf[(ksi2 << 5) + og2] = make_float4(p00, p01, p10, p11);
    }
    __syncthreads();
    if (t < 128) {
      // finisher: sum 8 K-partials, tanh, h update (published coherently)
      float sum = pf[t];
      #pragma unroll
      for (int q = 1; q < 8; ++q) sum += pf[(q << 7) + t];
      const float pre = sum + xv2;
      const float ex  = __expf(2.f * pre);
      const float y   = (ex - 1.f) / (ex + 1.f);
      const float hnew = (1.f - zv) * hold + zv * y;
      st_coh_f32(&hbuf[rowf2 * H_ + colblk + cf2], hnew);
      if (s == S_ - 1) yb[(b0 + rowf2) * H_ + colblk + cf2] = y;  // read by k_dense
    }

    group_barrier(gflags, myflag, ++nbar);                 // h_new visible group-wide
  }
}

// ---------------- dense head: out = y_T @ dense_W + dense_b ----------------
__global__ __launch_bounds__(256) void k_dense(
    const float* __restrict__ yb, const float* __restrict__ dW,
    const float* __restrict__ db, float* __restrict__ out)
{
  const int t = threadIdx.x;
  if (t >= 192) return;
  const int b = t / 3, p = t % 3;
  float acc = db[p];
  const float* yr = yb + b * H_;
  for (int k = 0; k < H_; ++k) acc = fmaf(yr[k], dW[k * 3 + p], acc);
  out[b * 3 + p] = acc;
}

// ---------------- launcher -------------------------------------------------
extern "C" void kernel_launch(void* const* d_in, const int* in_sizes, int n_in,
                              void* d_out, int out_size, void* d_ws, size_t ws_size,
                              hipStream_t stream) {
  const int*   text = (const int*)d_in[0];
  const float* emb  = (const float*)d_in[1];
  const float* Wz   = (const float*)d_in[2];
  const float* bz   = (const float*)d_in[3];
  const float* Wr   = (const float*)d_in[4];
  const float* br   = (const float*)d_in[5];
  const float* Wh   = (const float*)d_in[6];
  const float* bh   = (const float*)d_in[7];
  const float* dW   = (const float*)d_in[8];
  const float* db   = (const float*)d_in[9];
  float* out = (float*)d_out;

  // workspace layout
  float*    X    = (float*)d_ws;                                   // 201,326,592 B
  float*    hbp  = (float*)((char*)d_ws + (size_t)201326592);      // 8*8*512 f32
  float*    rbp  = hbp + 32768;
  float*    ybp  = rbp + 32768;
  unsigned* flgp = (unsigned*)(ybp + 32768);                       // 2048 words (32B/flag)

  hipLaunchKernelGGL(k_init, dim3(392), dim3(256), 0, stream, (unsigned*)hbp);

  hipLaunchKernelGGL(k_xproj, dim3(1024), dim3(256), 0, stream,
                     text, emb, Wz, Wr, Wh, bz, br, bh, X);

  const float* Wz_ = Wz; const float* Wr_ = Wr; const float* Wh_ = Wh;
  const float* X_ = X; float* hb_ = hbp; float* rb_ = rbp; float* yb_ = ybp;
  unsigned* flg_ = flgp;
  void* kargs[] = { (void*)&Wz_, (void*)&Wr_, (void*)&Wh_, (void*)&X_,
                    (void*)&hb_, (void*)&rb_, (void*)&yb_, (void*)&flg_ };
  hipLaunchCooperativeKernel((void*)k_gru, dim3(256), dim3(256), kargs, 0, stream);

  hipLaunchKernelGGL(k_dense, dim3(1), dim3(256), 0, stream, ybp, dW, db, out);
}

// Round 8
// 6239.019 us; speedup vs baseline: 2.6428x; 1.1238x over previous
//
#include <hip/hip_runtime.h>
#include <hip/hip_bf16.h>
#include <stdint.h>

#define B_ 64
#define S_ 512
#define E_ 300
#define H_ 512
#define NG_ 1536  // 3*H

// ---------------- init: zero h-state, r/y buffers, flags ---------------------
// hbuf(32768) + rbuf(32768) + ybuf(32768) + flags(8 groups * 32 slots * 8 = 2048) words
__global__ __launch_bounds__(256) void k_init(unsigned* __restrict__ p) {
  int i = blockIdx.x * 256 + threadIdx.x;
  if (i < 100352) p[i] = 0u;
}

// ---------------- kernel A: Xzrh[s][b][g*512+c] = x_{b,s} @ Wg[H:,:] + b_g ---
// 4 cols/thread, dwordx4 weight loads, xs broadcast reads. FMA order over e is
// ascending -> bit-identical to previous (validated absmax 0.0) version.
__global__ __launch_bounds__(256) void k_xproj(
    const int* __restrict__ text, const float* __restrict__ emb,
    const float* __restrict__ Wz, const float* __restrict__ Wr,
    const float* __restrict__ Wh, const float* __restrict__ bz,
    const float* __restrict__ br, const float* __restrict__ bh,
    float* __restrict__ X)
{
  __shared__ float xs[32][304];   // 32 (b,s)-rows x 300 embed dims (padded)
  __shared__ int   toks[32];
  const int b  = blockIdx.x >> 4;         // batch row
  const int s0 = (blockIdx.x & 15) << 5;  // 32-step tile
  const int t  = threadIdx.x;

  if (t < 32) toks[t] = text[b * S_ + s0 + t];
  __syncthreads();
  for (int r = 0; r < 32; ++r) {
    const float* er = emb + (size_t)toks[r] * E_;
    for (int e = t; e < E_; e += 256) xs[r][e] = er[e];
  }
  __syncthreads();

  const int c4 = t & 63;   // column quad id -> cols 4*c4..4*c4+3 within chunk
  const int q  = t >> 6;   // row quad: rows 8q..8q+7
  for (int chunk = 0; chunk < 6; ++chunk) {
    const int n  = chunk * 256 + (c4 << 2);
    const int g  = n >> 9;        // 0:z 1:r 2:h (uniform per chunk)
    const int bc = n & 511;
    const float* Wg = (g == 0) ? Wz : (g == 1) ? Wr : Wh;
    const float* bg = (g == 0) ? bz : (g == 1) ? br : bh;
    float acc[8][4];
    {
      const float4 bv = *(const float4*)&bg[bc];
      #pragma unroll
      for (int i = 0; i < 8; ++i) {
        acc[i][0] = bv.x; acc[i][1] = bv.y; acc[i][2] = bv.z; acc[i][3] = bv.w;
      }
    }
    for (int e = 0; e < E_; e += 4) {
      float w[4][4];
      #pragma unroll
      for (int ee = 0; ee < 4; ++ee)
        *(float4*)&w[ee][0] = *(const float4*)&Wg[(size_t)(H_ + e + ee) * H_ + bc];
      #pragma unroll
      for (int i = 0; i < 8; ++i) {
        float xv[4];
        *(float4*)xv = *(const float4*)&xs[(q << 3) + i][e];
        #pragma unroll
        for (int cc = 0; cc < 4; ++cc) {
          float a = acc[i][cc];
          #pragma unroll
          for (int ee = 0; ee < 4; ++ee) a = fmaf(xv[ee], w[ee][cc], a);
          acc[i][cc] = a;
        }
      }
    }
    #pragma unroll
    for (int i = 0; i < 8; ++i) {
      const int s = s0 + (q << 3) + i;
      *(float4*)&X[((size_t)s * B_ + b) * NG_ + n] =
          make_float4(acc[i][0], acc[i][1], acc[i][2], acc[i][3]);
    }
  }
}

// ---------------- coherent access primitives (intrinsics only) --------------
__device__ __forceinline__ unsigned ld_coh_u32(const unsigned* p) {
  return __hip_atomic_load(p, __ATOMIC_RELAXED, __HIP_MEMORY_SCOPE_AGENT);
}
__device__ __forceinline__ void st_coh_u32(unsigned* p, unsigned v) {
  __hip_atomic_store(p, v, __ATOMIC_RELAXED, __HIP_MEMORY_SCOPE_AGENT);
}
__device__ __forceinline__ void st_coh_f32(float* p, float v) {
  __hip_atomic_store(p, v, __ATOMIC_RELAXED, __HIP_MEMORY_SCOPE_AGENT);
}
// stage 8*512 floats group-state via u64 coherent loads: 8 loads/thread.
__device__ __forceinline__ void stage_coh(const float* src, float (*dst)[516], int t) {
  #pragma unroll
  for (int u = 0; u < 8; ++u) {
    const int e = (t << 1) + (u << 9);
    const unsigned long long v = __hip_atomic_load(
        (const unsigned long long*)(src + e), __ATOMIC_RELAXED, __HIP_MEMORY_SCOPE_AGENT);
    *(unsigned long long*)&dst[u][t << 1] = v;
  }
}

// poll half of the barrier; arrival (flag store) is done inline by caller
__device__ __forceinline__ void bar_poll(unsigned* gflags, unsigned gen, int t) {
  if (t < 64) {
    unsigned v;
    int it = 0;
    do {
      v = (t < 32) ? ld_coh_u32(gflags + t * 8) : gen;
    } while (__ballot(v < gen) && ++it < 4096);
  }
}

// ---------------- kernel B: persistent recurrence --------------------------
// grid 256: group g = bid%8 (8 batch rows), col-block j = bid/8 owns H-cols [16j,16j+16)
// LDS: 99072(WT) + 16512(hs) + 512(zs) + 4096(pbuf) = 120192 B -> 1 block/CU
__global__ __launch_bounds__(256, 1) void k_gru(
    const float* __restrict__ Wz, const float* __restrict__ Wr,
    const float* __restrict__ Wh, const float* __restrict__ X,
    float* __restrict__ hb, float* __restrict__ rb,
    float* __restrict__ yb, unsigned* __restrict__ flags)
{
  __shared__ float WT[48][516];   // [gate*16+c][k] transposed weights (99 KB)
  __shared__ float hs[8][516];    // h for the group's 8 rows; r*h in phase 2
  __shared__ float zs[8][16];     // own z slice
  __shared__ float pbuf[4][16][16]; // per-wave partial sums (4 KB, both phases)

  const int t = threadIdx.x;
  const int g = blockIdx.x & 7;
  const int j = blockIdx.x >> 3;
  const int colblk = j << 4;
  const int b0 = g << 3;

  float* hbuf = hb + g * (8 * H_);
  float* rbuf = rb + g * (8 * H_);
  unsigned* gflags = flags + g * 256;    // 32 flags * 8-dword (32B) stride
  unsigned* myflag = gflags + j * 8;

  // one-time: weights -> LDS (transposed so K is contiguous per gate-col)
  for (int idx = t; idx < 48 * 512; idx += 256) {
    const int gc = idx >> 9;
    const int k  = idx & 511;
    const float* Wsel = (gc < 16) ? Wz : (gc < 32) ? Wr : Wh;
    WT[gc][k] = Wsel[(size_t)k * H_ + colblk + (gc & 15)];
  }

  // ---- phase-1 compute mapping: 4x4 tile, K-split 16 (slice 32)
  const int tile1 = t & 15;       // rq = tile1&1 -> rows 4rq.., cq = tile1>>1 -> gcols 4cq..
  const int ksl1  = t >> 4;       // 0..15
  // ---- phase-1 finisher mapping: one output per thread (8 rows x 32 gcols)
  const int rowf  = t >> 5;       // 0..7
  const int gcolf = t & 31;       // 0..31
  const int gatef = gcolf >> 4;   // 0:z 1:r
  const int cf    = gcolf & 15;
  const int tilef = ((gcolf >> 2) << 1) | (rowf >> 2);
  const int af    = ((rowf & 3) << 2) | (gcolf & 3);
  // ---- phase-2 compute mapping: 4x4 tile, K-split 32 (slice 16)
  const int tile2 = t & 7;        // rq2 = tile2&1, cq2 = tile2>>1 -> cols 4cq2..
  const int ksl2  = t >> 3;       // 0..31
  // ---- phase-2 finisher mapping (t < 128): 8 rows x 16 cols
  const int rowf2  = t >> 4;      // valid for t<128
  const int cf2    = t & 15;
  const int tile2f = ((cf2 >> 2) << 1) | (rowf2 >> 2);
  const int af2    = ((rowf2 & 3) << 2) | (cf2 & 3);

  const int off1 = rowf * NG_ + gatef * H_ + colblk + cf;
  const int off2 = rowf2 * NG_ + 2 * H_ + colblk + cf2;

  unsigned nbar = 0;
  __syncthreads();

  // prologue: prefetch X operands for s=0
  const float* X0 = X + (size_t)b0 * NG_;
  float xv1p = X0[off1];
  float xv2p = (t < 128) ? X0[off2] : 0.f;

  for (int s = 0; s < S_; ++s) {
    // stage h (coherent u64 loads) -> hs
    stage_coh(hbuf, hs, t);
    __syncthreads();

    // ---- phase 1: z,r = sigmoid(h @ W + X) ; 4x4 block, K-split 16 ----
    {
      const int r0 = (tile1 & 1) << 2;
      const int c0 = (tile1 >> 1) << 2;
      const int k0 = ksl1 << 5;
      float acc[16];
      #pragma unroll
      for (int a = 0; a < 16; ++a) acc[a] = 0.f;
      #pragma unroll
      for (int kk = 0; kk < 32; kk += 4) {
        const int k = k0 + kk;
        float4 hv[4], wv[4];
        #pragma unroll
        for (int ri = 0; ri < 4; ++ri) hv[ri] = *(const float4*)&hs[r0 + ri][k];
        #pragma unroll
        for (int ci = 0; ci < 4; ++ci) wv[ci] = *(const float4*)&WT[c0 + ci][k];
        #pragma unroll
        for (int ri = 0; ri < 4; ++ri)
          #pragma unroll
          for (int ci = 0; ci < 4; ++ci) {
            float a = acc[(ri << 2) | ci];
            a = fmaf(hv[ri].x, wv[ci].x, a);
            a = fmaf(hv[ri].y, wv[ci].y, a);
            a = fmaf(hv[ri].z, wv[ci].z, a);
            a = fmaf(hv[ri].w, wv[ci].w, a);
            acc[(ri << 2) | ci] = a;
          }
      }
      // reduce K-splits within the wave (ksl1 spans 4 values per wave)
      #pragma unroll
      for (int a = 0; a < 16; ++a) {
        acc[a] += __shfl_xor(acc[a], 16);
        acc[a] += __shfl_xor(acc[a], 32);
      }
      if ((t & 48) == 0) {           // lanes 0-15 of each wave
        const int w = t >> 6;
        #pragma unroll
        for (int a4 = 0; a4 < 4; ++a4)
          *(float4*)&pbuf[w][tile1][a4 << 2] =
              make_float4(acc[a4 * 4], acc[a4 * 4 + 1], acc[a4 * 4 + 2], acc[a4 * 4 + 3]);
      }
    }
    __syncthreads();
    {
      // finisher: sum 4 wave-partials, add X, sigmoid; publish r*h
      const float sum = pbuf[0][tilef][af] + pbuf[1][tilef][af]
                      + pbuf[2][tilef][af] + pbuf[3][tilef][af];
      const float pre = sum + xv1p;
      const float sig = 1.f / (1.f + __expf(-pre));
      if (gatef == 0) zs[rowf][cf] = sig;                              // z local
      else st_coh_f32(&rbuf[rowf * H_ + colblk + cf],
                      sig * hs[rowf][colblk + cf]);                    // publish r*h
    }

    // ---- barrier 1 (arrive early, snapshot, poll late) ----
    __syncthreads();                       // drains r*h stores (vmcnt0 + barrier)
    ++nbar;
    if (t == 0) st_coh_u32(myflag, nbar);
    float hold = 0.f, zv = 0.f;
    if (t < 128) { hold = hs[rowf2][colblk + cf2]; zv = zs[rowf2][cf2]; }
    bar_poll(gflags, nbar, t);
    __syncthreads();

    // stage r*h (coherent) -> hs, overwriting h
    stage_coh(rbuf, hs, t);
    __syncthreads();

    // ---- phase 2: y = tanh((r*h) @ Wh + Xh) ; 4x4 block, K-split 32 ----
    {
      const int r0 = (tile2 & 1) << 2;
      const int c0 = (tile2 >> 1) << 2;
      const int k0 = ksl2 << 4;
      float acc[16];
      #pragma unroll
      for (int a = 0; a < 16; ++a) acc[a] = 0.f;
      #pragma unroll
      for (int kk = 0; kk < 16; kk += 4) {
        const int k = k0 + kk;
        float4 hv[4], wv[4];
        #pragma unroll
        for (int ri = 0; ri < 4; ++ri) hv[ri] = *(const float4*)&hs[r0 + ri][k];
        #pragma unroll
        for (int ci = 0; ci < 4; ++ci) wv[ci] = *(const float4*)&WT[32 + c0 + ci][k];
        #pragma unroll
        for (int ri = 0; ri < 4; ++ri)
          #pragma unroll
          for (int ci = 0; ci < 4; ++ci) {
            float a = acc[(ri << 2) | ci];
            a = fmaf(hv[ri].x, wv[ci].x, a);
            a = fmaf(hv[ri].y, wv[ci].y, a);
            a = fmaf(hv[ri].z, wv[ci].z, a);
            a = fmaf(hv[ri].w, wv[ci].w, a);
            acc[(ri << 2) | ci] = a;
          }
      }
      // reduce K-splits within the wave (ksl2 spans 8 values per wave)
      #pragma unroll
      for (int a = 0; a < 16; ++a) {
        acc[a] += __shfl_xor(acc[a], 8);
        acc[a] += __shfl_xor(acc[a], 16);
        acc[a] += __shfl_xor(acc[a], 32);
      }
      if ((t & 56) == 0) {           // lanes 0-7 of each wave
        const int w = t >> 6;
        #pragma unroll
        for (int a4 = 0; a4 < 4; ++a4)
          *(float4*)&pbuf[w][tile2][a4 << 2] =
              make_float4(acc[a4 * 4], acc[a4 * 4 + 1], acc[a4 * 4 + 2], acc[a4 * 4 + 3]);
      }
    }
    __syncthreads();
    if (t < 128) {
      // finisher: sum 4 wave-partials, tanh, h update (published coherently)
      const float sum = pbuf[0][tile2f][af2] + pbuf[1][tile2f][af2]
                      + pbuf[2][tile2f][af2] + pbuf[3][tile2f][af2];
      const float pre = sum + xv2p;
      const float ex  = __expf(2.f * pre);
      const float y   = (ex - 1.f) / (ex + 1.f);
      const float hnew = (1.f - zv) * hold + zv * y;
      st_coh_f32(&hbuf[rowf2 * H_ + colblk + cf2], hnew);
      if (s == S_ - 1) yb[(b0 + rowf2) * H_ + colblk + cf2] = y;  // read by k_dense
    }

    // ---- barrier 2 (arrive early, prefetch next X, poll late) ----
    __syncthreads();                       // drains h stores
    ++nbar;
    if (t == 0) st_coh_u32(myflag, nbar);
    {
      const int sn = (s < S_ - 1) ? s + 1 : s;
      const float* Xn = X + ((size_t)sn * B_ + b0) * NG_;
      xv1p = Xn[off1];
      if (t < 128) xv2p = Xn[off2];
    }
    bar_poll(gflags, nbar, t);
    __syncthreads();
  }
}

// ---------------- dense head: out = y_T @ dense_W + dense_b ----------------
__global__ __launch_bounds__(256) void k_dense(
    const float* __restrict__ yb, const float* __restrict__ dW,
    const float* __restrict__ db, float* __restrict__ out)
{
  const int t = threadIdx.x;
  if (t >= 192) return;
  const int b = t / 3, p = t % 3;
  float acc = db[p];
  const float* yr = yb + b * H_;
  for (int k = 0; k < H_; ++k) acc = fmaf(yr[k], dW[k * 3 + p], acc);
  out[b * 3 + p] = acc;
}

// ---------------- launcher -------------------------------------------------
extern "C" void kernel_launch(void* const* d_in, const int* in_sizes, int n_in,
                              void* d_out, int out_size, void* d_ws, size_t ws_size,
                              hipStream_t stream) {
  const int*   text = (const int*)d_in[0];
  const float* emb  = (const float*)d_in[1];
  const float* Wz   = (const float*)d_in[2];
  const float* bz   = (const float*)d_in[3];
  const float* Wr   = (const float*)d_in[4];
  const float* br   = (const float*)d_in[5];
  const float* Wh   = (const float*)d_in[6];
  const float* bh   = (const float*)d_in[7];
  const float* dW   = (const float*)d_in[8];
  const float* db   = (const float*)d_in[9];
  float* out = (float*)d_out;

  // workspace layout
  float*    X    = (float*)d_ws;                                   // 201,326,592 B
  float*    hbp  = (float*)((char*)d_ws + (size_t)201326592);      // 8*8*512 f32
  float*    rbp  = hbp + 32768;
  float*    ybp  = rbp + 32768;
  unsigned* flgp = (unsigned*)(ybp + 32768);                       // 2048 words (32B/flag)

  hipLaunchKernelGGL(k_init, dim3(392), dim3(256), 0, stream, (unsigned*)hbp);

  hipLaunchKernelGGL(k_xproj, dim3(1024), dim3(256), 0, stream,
                     text, emb, Wz, Wr, Wh, bz, br, bh, X);

  const float* Wz_ = Wz; const float* Wr_ = Wr; const float* Wh_ = Wh;
  const float* X_ = X; float* hb_ = hbp; float* rb_ = rbp; float* yb_ = ybp;
  unsigned* flg_ = flgp;
  void* kargs[] = { (void*)&Wz_, (void*)&Wr_, (void*)&Wh_, (void*)&X_,
                    (void*)&hb_, (void*)&rb_, (void*)&yb_, (void*)&flg_ };
  hipLaunchCooperativeKernel((void*)k_gru, dim3(256), dim3(256), kargs, 0, stream);

  hipLaunchKernelGGL(k_dense, dim3(1), dim3(256), 0, stream, ybp, dW, db, out);
}